// Round 7
// baseline (12720.658 us; speedup 1.0000x reference)
//
#include <hip/hip_runtime.h>

// ---------------------------------------------------------------------------
// SimpleGPT forward on MI355X. Round 7: 192x192 GEMM tile (LDS bytes/FLOP
// cut 1.8x), grid swapped m-fastest for B L2 reuse. R6's A-direct-global
// regressed (latency-exposed) -> reverted to both-operands-in-LDS.
//   gemm192: BM=BN=192 BK=32, 4 waves 2x2, wave 96x96 (6x6 mfma 16x16x32),
//   acc 144 VGPR, launch_bounds(256,2). Staging loads for next iter issued
//   under current iter's MFMA bundle.
// ---------------------------------------------------------------------------

#define B_  2048
#define T_  60
#define C_  384
#define H_  6
#define HS_ 64
#define L_  6
#define FF_ 1536
#define V_  65

typedef unsigned int  u32;
typedef unsigned short u16;
typedef short bf16x8 __attribute__((ext_vector_type(8)));
typedef float f32x4  __attribute__((ext_vector_type(4)));

__device__ __forceinline__ float bf2f(u32 u) {
  return __uint_as_float(u << 16);
}
__device__ __forceinline__ u16 f2bf(float f) {
  u32 u = __float_as_uint(f);
  u = u + 0x7FFFu + ((u >> 16) & 1u);   // RNE; inputs are finite
  return (u16)(u >> 16);
}

// ------------------------------------------------ weight transpose+convert
__global__ void tconv_k(const float* __restrict__ src, u16* __restrict__ dst,
                        int K, int N, long srcStride, int nH, long sL, long sH)
{
  __shared__ float t[32][33];
  int z = blockIdx.z;
  int l = z / nH, hh = z % nH;
  const float* s = src + (long)z * srcStride;
  u16* d = dst + l * sL + hh * sH;
  int n0 = blockIdx.x * 32, k0 = blockIdx.y * 32;
  for (int yy = threadIdx.y; yy < 32; yy += 8) {
    int k = k0 + yy, n = n0 + threadIdx.x;
    t[yy][threadIdx.x] = (k < K && n < N) ? s[(long)k * N + n] : 0.f;
  }
  __syncthreads();
  for (int yy = threadIdx.y; yy < 32; yy += 8) {
    int n = n0 + yy, k = k0 + threadIdx.x;
    if (n < N && k < K) d[(long)n * K + k] = f2bf(t[threadIdx.x][yy]);
  }
}

// ---------------------------------------------------------------- embedding
__global__ __launch_bounds__(256) void embed_k(const int* __restrict__ ctx,
    const float* __restrict__ tok, const float* __restrict__ pos,
    float* __restrict__ x)
{
  int idx = blockIdx.x * 256 + threadIdx.x;
  int row = idx / (C_ / 4);
  int c   = (idx % (C_ / 4)) * 4;
  int t   = row % T_;
  int tk  = ctx[row];
  float4 a = *(const float4*)(tok + (long)tk * C_ + c);
  float4 p = *(const float4*)(pos + (long)t  * C_ + c);
  float4 o = make_float4(a.x + p.x, a.y + p.y, a.z + p.z, a.w + p.w);
  *(float4*)(x + (long)idx * 4) = o;
}

// ---------------------------------------------------------------- layernorm
__global__ __launch_bounds__(256) void ln_k(const float* __restrict__ x,
    const float* __restrict__ g, const float* __restrict__ b,
    u16* __restrict__ h)
{
  int lane = threadIdx.x & 63;
  int wv   = threadIdx.x >> 6;
  long row = (long)blockIdx.x * 4 + wv;
  const float* xr = x + row * C_;
  int c0 = lane * 6;
  float v0[6];
  #pragma unroll
  for (int i = 0; i < 6; i++) v0[i] = xr[c0 + i];
  float s = 0.f, sq = 0.f;
  #pragma unroll
  for (int i = 0; i < 6; i++) { s += v0[i]; sq += v0[i] * v0[i]; }
  #pragma unroll
  for (int off = 32; off > 0; off >>= 1) {
    s  += __shfl_xor(s,  off, 64);
    sq += __shfl_xor(sq, off, 64);
  }
  float mu  = s * (1.f / C_);
  float var = sq * (1.f / C_) - mu * mu;
  float rs  = rsqrtf(var + 1e-5f);
  u16* hr = h + row * C_;
  #pragma unroll
  for (int i = 0; i < 6; i++) {
    float hv = (v0[i] - mu) * rs * g[c0 + i] + b[c0 + i];
    hr[c0 + i] = f2bf(hv);
  }
}

// ------------------------------------------------------------- MFMA GEMM 192
// out[M,N] = act(A[M,K](bf16) @ Wt^T + bias) [+ resid]; Wt bf16 [N][K].
// M%192==0, N%192==0, K%32==0. grid (x=mtiles, y=ntiles).
template<int RELU, int RES, int OBF>
__global__ __launch_bounds__(256, 2) void gemm192(const u16* __restrict__ A,
    const u16* __restrict__ Wt, const float* __restrict__ bias,
    const float* __restrict__ resid, void* __restrict__ outp, int N, int K)
{
  __shared__ __align__(16) u16 As[4][192][8];   // [kseg][row][kj] 12 KB
  __shared__ __align__(16) u16 Bs[4][192][8];   // [kseg][col][kj] 12 KB
  int tid = threadIdx.x;
  long mBase = (long)blockIdx.x * 192;
  int nBase = blockIdx.y * 192;
  int lane = tid & 63, wv = tid >> 6;
  int l15 = lane & 15, quad = lane >> 4;
  int wr = (wv & 1) * 96;
  int wc = (wv >> 1) * 96;
  int sk = tid & 3;            // staging kseg
  int sr = tid >> 2;           // staging row base (0..63), +64, +128

  const u16* aP = A + (mBase + sr) * (long)K + sk * 8;
  const u16* bP = Wt + ((long)nBase + sr) * K + sk * 8;
  const long rowStep = (long)64 * K;

  f32x4 acc[6][6];
  #pragma unroll
  for (int i = 0; i < 6; i++)
    #pragma unroll
    for (int j = 0; j < 6; j++)
      acc[i][j] = (f32x4){0.f, 0.f, 0.f, 0.f};

  uint4 a_st[3], b_st[3];
  #pragma unroll
  for (int i = 0; i < 3; i++) {
    a_st[i] = *(const uint4*)(aP + i * rowStep);
    b_st[i] = *(const uint4*)(bP + i * rowStep);
  }

  for (int k0 = 0; k0 < K; k0 += 32) {
    #pragma unroll
    for (int i = 0; i < 3; i++) {
      *(uint4*)&As[sk][sr + i * 64][0] = a_st[i];
      *(uint4*)&Bs[sk][sr + i * 64][0] = b_st[i];
    }
    __syncthreads();
    bf16x8 af[6], bf[6];
    #pragma unroll
    for (int i = 0; i < 6; i++) {
      af[i] = *(const bf16x8*)&As[quad][wr + i * 16 + l15][0];
      bf[i] = *(const bf16x8*)&Bs[quad][wc + i * 16 + l15][0];
    }
    if (k0 + 32 < K) {
      #pragma unroll
      for (int i = 0; i < 3; i++) {
        a_st[i] = *(const uint4*)(aP + i * rowStep + k0 + 32);
        b_st[i] = *(const uint4*)(bP + i * rowStep + k0 + 32);
      }
    }
    #pragma unroll
    for (int i = 0; i < 6; i++)
      #pragma unroll
      for (int j = 0; j < 6; j++)
        acc[i][j] = __builtin_amdgcn_mfma_f32_16x16x32_bf16(
            af[i], bf[j], acc[i][j], 0, 0, 0);
    __syncthreads();
  }

  #pragma unroll
  for (int j = 0; j < 6; j++) {
    int n = nBase + wc + j * 16 + l15;
    float bv = bias ? bias[n] : 0.f;
    #pragma unroll
    for (int i = 0; i < 6; i++) {
      #pragma unroll
      for (int r = 0; r < 4; r++) {
        long row = mBase + wr + i * 16 + quad * 4 + r;
        float vv = acc[i][j][r] + bv;
        if (RELU) vv = fmaxf(vv, 0.f);
        if (RES)  vv += resid[row * N + n];
        if (OBF) ((u16*)outp)[row * N + n] = f2bf(vv);
        else     ((float*)outp)[row * N + n] = vv;
      }
    }
  }
}

// ------------------------------------------------------------- head GEMM
template<int OBF>
__global__ __launch_bounds__(256) void gemm_head(const u16* __restrict__ A,
    const u16* __restrict__ Wt, const float* __restrict__ bias,
    void* __restrict__ outp, int N, int K)
{
  __shared__ __align__(16) u16 As[4][128][8];
  __shared__ __align__(16) u16 Bs[4][64][8];
  int tid  = threadIdx.x;
  int nt   = blockIdx.x;
  int nBase = nt * 64;
  long mBase = (long)blockIdx.y * 128;
  int lane = tid & 63, wv = tid >> 6;
  int l15 = lane & 15, l4 = lane >> 4;
  int sseg = tid & 3;
  int srow = tid >> 2;
  const u16* a0p = A + (mBase + srow) * K + sseg * 8;
  const u16* a1p = a0p + (long)64 * K;
  bool colOK = (nBase + srow) < N;
  const u16* bp  = Wt + (long)(nBase + srow) * K + sseg * 8;

  f32x4 acc[2][4];
  #pragma unroll
  for (int i = 0; i < 2; i++)
    #pragma unroll
    for (int j = 0; j < 4; j++)
      acc[i][j] = (f32x4){0.f, 0.f, 0.f, 0.f};

  for (int k0 = 0; k0 < K; k0 += 32) {
    uint4 av0 = *(const uint4*)(a0p + k0);
    uint4 av1 = *(const uint4*)(a1p + k0);
    uint4 bv  = colOK ? *(const uint4*)(bp + k0) : make_uint4(0, 0, 0, 0);
    *(uint4*)&As[sseg][srow][0]      = av0;
    *(uint4*)&As[sseg][srow + 64][0] = av1;
    *(uint4*)&Bs[sseg][srow][0]      = bv;
    __syncthreads();
    bf16x8 af[2], bfr[4];
    af[0] = *(const bf16x8*)&As[l4][wv * 32 + l15][0];
    af[1] = *(const bf16x8*)&As[l4][wv * 32 + 16 + l15][0];
    #pragma unroll
    for (int j = 0; j < 4; j++)
      bfr[j] = *(const bf16x8*)&Bs[l4][j * 16 + l15][0];
    #pragma unroll
    for (int i = 0; i < 2; i++)
      #pragma unroll
      for (int j = 0; j < 4; j++)
        acc[i][j] = __builtin_amdgcn_mfma_f32_16x16x32_bf16(
            af[i], bfr[j], acc[i][j], 0, 0, 0);
    __syncthreads();
  }

  #pragma unroll
  for (int i = 0; i < 2; i++) {
    #pragma unroll
    for (int j = 0; j < 4; j++) {
      int n = nBase + j * 16 + l15;
      if (n < N) {
        #pragma unroll
        for (int r = 0; r < 4; r++) {
          long row = mBase + wv * 32 + i * 16 + l4 * 4 + r;
          float vv = acc[i][j][r];
          if (bias) vv += bias[n];
          if (OBF) ((u16*)outp)[row * N + n] = f2bf(vv);
          else     ((float*)outp)[row * N + n] = vv;
        }
      }
    }
  }
}

// ---------------------------------------------------------------- attention
// MFMA flash-style: one block per (b, head); qkv [BTc][1152]; ao [BTc][384].
__global__ __launch_bounds__(256) void attn_k(const u16* __restrict__ qkv,
    u16* __restrict__ ao)
{
  __shared__ __align__(16) u16 qs[64][72];
  __shared__ __align__(16) u16 ks[64][72];
  __shared__ __align__(16) u16 vT[64][72];
  __shared__ __align__(16) u16 ps[64][72];
  int tid = threadIdx.x;
  int bb = blockIdx.x / H_;
  int hh = blockIdx.x % H_;
  const u16* base = qkv + ((long)bb * T_) * 1152 + hh * HS_;

  for (int i = tid; i < 576; i += 256)
    ((uint4*)vT)[i] = make_uint4(0, 0, 0, 0);
  __syncthreads();

  for (int i = tid; i < 480; i += 256) {
    int t = i >> 3, d0 = (i & 7) << 3;
    const u16* rp = base + (long)t * 1152;
    *(uint4*)&qs[t][d0] = *(const uint4*)(rp + d0);
    *(uint4*)&ks[t][d0] = *(const uint4*)(rp + 384 + d0);
    uint4 rv = *(const uint4*)(rp + 768 + d0);
    u16 vv[8] = {(u16)(rv.x & 0xffffu), (u16)(rv.x >> 16),
                 (u16)(rv.y & 0xffffu), (u16)(rv.y >> 16),
                 (u16)(rv.z & 0xffffu), (u16)(rv.z >> 16),
                 (u16)(rv.w & 0xffffu), (u16)(rv.w >> 16)};
    #pragma unroll
    for (int m = 0; m < 8; m++) vT[d0 + m][t] = vv[m];
  }
  __syncthreads();

  int lane = tid & 63, wv = tid >> 6;
  int l15 = lane & 15, quad = lane >> 4;

  bf16x8 aq0 = *(const bf16x8*)&qs[wv * 16 + l15][quad * 8];
  bf16x8 aq1 = *(const bf16x8*)&qs[wv * 16 + l15][32 + quad * 8];
  f32x4 s[4];
  #pragma unroll
  for (int jt = 0; jt < 4; jt++) {
    bf16x8 b0 = *(const bf16x8*)&ks[jt * 16 + l15][quad * 8];
    bf16x8 b1 = *(const bf16x8*)&ks[jt * 16 + l15][32 + quad * 8];
    f32x4 a2 = (f32x4){0.f, 0.f, 0.f, 0.f};
    a2 = __builtin_amdgcn_mfma_f32_16x16x32_bf16(aq0, b0, a2, 0, 0, 0);
    a2 = __builtin_amdgcn_mfma_f32_16x16x32_bf16(aq1, b1, a2, 0, 0, 0);
    s[jt] = a2;
  }

  int rbase = wv * 16 + quad * 4;
  #pragma unroll
  for (int r = 0; r < 4; r++) {
    int row = rbase + r;
    float v0[4];
    #pragma unroll
    for (int jt = 0; jt < 4; jt++) {
      int col = jt * 16 + l15;
      float sv = s[jt][r] * 0.125f;
      v0[jt] = (col <= row) ? sv : -1e30f;
    }
    float m = fmaxf(fmaxf(v0[0], v0[1]), fmaxf(v0[2], v0[3]));
    #pragma unroll
    for (int off = 1; off < 16; off <<= 1) m = fmaxf(m, __shfl_xor(m, off, 64));
    float sum = 0.f;
    #pragma unroll
    for (int jt = 0; jt < 4; jt++) { v0[jt] = __expf(v0[jt] - m); sum += v0[jt]; }
    #pragma unroll
    for (int off = 1; off < 16; off <<= 1) sum += __shfl_xor(sum, off, 64);
    float inv = 1.f / sum;
    #pragma unroll
    for (int jt = 0; jt < 4; jt++)
      ps[row][jt * 16 + l15] = f2bf(v0[jt] * inv);
  }
  __syncthreads();

  bf16x8 ap0 = *(const bf16x8*)&ps[wv * 16 + l15][quad * 8];
  bf16x8 ap1 = *(const bf16x8*)&ps[wv * 16 + l15][32 + quad * 8];
  long obase = ((long)bb * T_) * C_ + hh * HS_;
  #pragma unroll
  for (int dt = 0; dt < 4; dt++) {
    bf16x8 b0 = *(const bf16x8*)&vT[dt * 16 + l15][quad * 8];
    bf16x8 b1 = *(const bf16x8*)&vT[dt * 16 + l15][32 + quad * 8];
    f32x4 a2 = (f32x4){0.f, 0.f, 0.f, 0.f};
    a2 = __builtin_amdgcn_mfma_f32_16x16x32_bf16(ap0, b0, a2, 0, 0, 0);
    a2 = __builtin_amdgcn_mfma_f32_16x16x32_bf16(ap1, b1, a2, 0, 0, 0);
    #pragma unroll
    for (int r = 0; r < 4; r++) {
      int row = rbase + r;
      if (row < T_)
        ao[obase + (long)row * C_ + dt * 16 + l15] = f2bf(a2[r]);
    }
  }
}

// ---------------------------------------------------------------- launch
extern "C" void kernel_launch(void* const* d_in, const int* in_sizes, int n_in,
                              void* d_out, int out_size, void* d_ws, size_t ws_size,
                              hipStream_t stream)
{
  const int*   ctx  = (const int*)  d_in[0];
  const float* tok  = (const float*)d_in[1];
  const float* pos  = (const float*)d_in[2];
  const float* wq   = (const float*)d_in[3];
  const float* wk   = (const float*)d_in[4];
  const float* wv   = (const float*)d_in[5];
  const float* wo   = (const float*)d_in[6];
  const float* bo   = (const float*)d_in[7];
  const float* ln1g = (const float*)d_in[8];
  const float* ln1b = (const float*)d_in[9];
  const float* ln2g = (const float*)d_in[10];
  const float* ln2b = (const float*)d_in[11];
  const float* w1   = (const float*)d_in[12];
  const float* b1   = (const float*)d_in[13];
  const float* w2   = (const float*)d_in[14];
  const float* b2   = (const float*)d_in[15];
  const float* lnfg = (const float*)d_in[16];
  const float* lnfb = (const float*)d_in[17];
  const float* lmw  = (const float*)d_in[18];
  const float* lmb  = (const float*)d_in[19];
  float* out = (float*)d_out;

  const long nQKV = (long)L_ * H_ * C_ * HS_;
  const long nWO  = (long)L_ * C_ * C_;
  const long nW1  = (long)L_ * C_ * FF_;
  const long nLM  = (long)C_ * V_;
  u16* wqkvT = (u16*)d_ws;                       // [L][1152][384]
  u16* woT = wqkvT + 3 * nQKV;
  u16* w1T = woT + nWO;
  u16* w2T = w1T + nW1;
  u16* lmT = w2T + nW1;
  const size_t wbytes = (size_t)(nQKV * 3 + nWO + nW1 * 2 + nLM) * 2;

  int chunkB = 32;
  {
    const int cand[] = {2048, 1024, 512, 256, 128, 64, 32};
    for (int i = 0; i < 7; i++) {
      size_t U = (size_t)cand[i] * T_ * C_ * 2;
      if (wbytes + 7 * U <= ws_size) { chunkB = cand[i]; break; }
    }
  }
  const long BTc = (long)chunkB * T_;
  char* wsb = (char*)d_ws + wbytes;
  const size_t U = (size_t)BTc * C_ * 2;
  float* x    = (float*)wsb;             // 2U
  u16*   h    = (u16*)(wsb + 2 * U);     // 1U
  char*  reg  = wsb + 3 * U;             // 4U: qkv(3U) + ab(1U); fb aliases
  u16* qkvb = (u16*)reg;
  u16* ab   = (u16*)(reg + 3 * U);
  u16* fb   = (u16*)reg;                 // alias: qkv/ab dead before MLP

  {
    dim3 tb(32, 8);
    const long sL = 1152L * 384, sH = 64L * 384, sec = 384L * 384;
    tconv_k<<<dim3(2, 12, L_ * H_), tb, 0, stream>>>(wq, wqkvT,
        C_, HS_, (long)C_ * HS_, H_, sL, sH);
    tconv_k<<<dim3(2, 12, L_ * H_), tb, 0, stream>>>(wk, wqkvT + sec,
        C_, HS_, (long)C_ * HS_, H_, sL, sH);
    tconv_k<<<dim3(2, 12, L_ * H_), tb, 0, stream>>>(wv, wqkvT + 2 * sec,
        C_, HS_, (long)C_ * HS_, H_, sL, sH);
    tconv_k<<<dim3(12, 12, L_), tb, 0, stream>>>(wo, woT,
        C_, C_, (long)C_ * C_, 1, (long)C_ * C_, 0);
    tconv_k<<<dim3(48, 12, L_), tb, 0, stream>>>(w1, w1T,
        C_, FF_, (long)C_ * FF_, 1, (long)C_ * FF_, 0);
    tconv_k<<<dim3(12, 48, L_), tb, 0, stream>>>(w2, w2T,
        FF_, C_, (long)FF_ * C_, 1, (long)FF_ * C_, 0);
    tconv_k<<<dim3(3, 12, 1), tb, 0, stream>>>(lmw, lmT,
        C_, V_, (long)C_ * V_, 1, 0, 0);
  }

  const long qkvL = 1152L * 384;
  const long woL  = (long)C_ * C_;
  const long w1L  = (long)C_ * FF_;
  dim3 blk(256);
  dim3 gEmb((u32)(BTc * C_ / 4 / 256));
  dim3 gLN((u32)(BTc / 4));
  u32 mT = (u32)(BTc / 192);
  dim3 gQKV(mT, 6), gWO(mT, 2), gW1(mT, 8), gW2(mT, 2);
  dim3 gHd(2, (u32)(BTc / 128));
  dim3 gAt((u32)(chunkB * H_));

  for (int c0 = 0; c0 < B_; c0 += chunkB) {
    const long tok0 = (long)c0 * T_;
    const int* ctxc = ctx + tok0;
    float* outc = out + tok0 * V_;

    embed_k<<<gEmb, blk, 0, stream>>>(ctxc, tok, pos, x);

    for (int l = 0; l < L_; l++) {
      ln_k<<<gLN, blk, 0, stream>>>(x, ln1g + l * C_, ln1b + l * C_, h);
      gemm192<0,0,1><<<gQKV, blk, 0, stream>>>(h, wqkvT + l * qkvL,
          nullptr, nullptr, qkvb, 1152, C_);
      attn_k<<<gAt, blk, 0, stream>>>(qkvb, ab);
      gemm192<0,1,0><<<gWO, blk, 0, stream>>>(ab, woT + l * woL,
          bo + l * C_, x, x, C_, C_);
      ln_k<<<gLN, blk, 0, stream>>>(x, ln2g + l * C_, ln2b + l * C_, h);
      gemm192<1,0,1><<<gW1, blk, 0, stream>>>(h, w1T + l * w1L,
          b1 + l * FF_, nullptr, fb, FF_, C_);
      gemm192<0,1,0><<<gW2, blk, 0, stream>>>(fb, w2T + l * w1L,
          b2 + l * C_, x, x, C_, FF_);
    }

    ln_k<<<gLN, blk, 0, stream>>>(x, lnfg, lnfb, h);
    gemm_head<0><<<gHd, blk, 0, stream>>>(h, lmT, lmb, outc, V_, C_);
  }
}

// Round 8
// 5962.186 us; speedup vs baseline: 2.1336x; 2.1336x over previous
//
#include <hip/hip_runtime.h>

// ---------------------------------------------------------------------------
// SimpleGPT forward on MI355X. Round 8: R5 gemm128 base (best, 7.11ms) +
//   (a) LDS double-buffer -> ONE barrier per k-iter (R5 had 2x12),
//   (b) XCD-aware block swizzle (1-D grid): all ntiles of an mtile on one
//       XCD -> A-tile L2-resident (R5 FETCH showed ~4x A re-fetch).
// R7's 192-tile spilled (VGPR 144 acc) -> reverted entirely.
// ---------------------------------------------------------------------------

#define B_  2048
#define T_  60
#define C_  384
#define H_  6
#define HS_ 64
#define L_  6
#define FF_ 1536
#define V_  65

typedef unsigned int  u32;
typedef unsigned short u16;
typedef short bf16x8 __attribute__((ext_vector_type(8)));
typedef float f32x4  __attribute__((ext_vector_type(4)));

__device__ __forceinline__ float bf2f(u32 u) {
  return __uint_as_float(u << 16);
}
__device__ __forceinline__ u16 f2bf(float f) {
  u32 u = __float_as_uint(f);
  u = u + 0x7FFFu + ((u >> 16) & 1u);   // RNE; inputs are finite
  return (u16)(u >> 16);
}

// ------------------------------------------------ weight transpose+convert
__global__ void tconv_k(const float* __restrict__ src, u16* __restrict__ dst,
                        int K, int N, long srcStride, int nH, long sL, long sH)
{
  __shared__ float t[32][33];
  int z = blockIdx.z;
  int l = z / nH, hh = z % nH;
  const float* s = src + (long)z * srcStride;
  u16* d = dst + l * sL + hh * sH;
  int n0 = blockIdx.x * 32, k0 = blockIdx.y * 32;
  for (int yy = threadIdx.y; yy < 32; yy += 8) {
    int k = k0 + yy, n = n0 + threadIdx.x;
    t[yy][threadIdx.x] = (k < K && n < N) ? s[(long)k * N + n] : 0.f;
  }
  __syncthreads();
  for (int yy = threadIdx.y; yy < 32; yy += 8) {
    int n = n0 + yy, k = k0 + threadIdx.x;
    if (n < N && k < K) d[(long)n * K + k] = f2bf(t[threadIdx.x][yy]);
  }
}

// ---------------------------------------------------------------- embedding
__global__ __launch_bounds__(256) void embed_k(const int* __restrict__ ctx,
    const float* __restrict__ tok, const float* __restrict__ pos,
    float* __restrict__ x)
{
  int idx = blockIdx.x * 256 + threadIdx.x;
  int row = idx / (C_ / 4);
  int c   = (idx % (C_ / 4)) * 4;
  int t   = row % T_;
  int tk  = ctx[row];
  float4 a = *(const float4*)(tok + (long)tk * C_ + c);
  float4 p = *(const float4*)(pos + (long)t  * C_ + c);
  float4 o = make_float4(a.x + p.x, a.y + p.y, a.z + p.z, a.w + p.w);
  *(float4*)(x + (long)idx * 4) = o;
}

// ---------------------------------------------------------------- layernorm
__global__ __launch_bounds__(256) void ln_k(const float* __restrict__ x,
    const float* __restrict__ g, const float* __restrict__ b,
    u16* __restrict__ h)
{
  int lane = threadIdx.x & 63;
  int wv   = threadIdx.x >> 6;
  long row = (long)blockIdx.x * 4 + wv;
  const float* xr = x + row * C_;
  int c0 = lane * 6;
  float v0[6];
  #pragma unroll
  for (int i = 0; i < 6; i++) v0[i] = xr[c0 + i];
  float s = 0.f, sq = 0.f;
  #pragma unroll
  for (int i = 0; i < 6; i++) { s += v0[i]; sq += v0[i] * v0[i]; }
  #pragma unroll
  for (int off = 32; off > 0; off >>= 1) {
    s  += __shfl_xor(s,  off, 64);
    sq += __shfl_xor(sq, off, 64);
  }
  float mu  = s * (1.f / C_);
  float var = sq * (1.f / C_) - mu * mu;
  float rs  = rsqrtf(var + 1e-5f);
  u16* hr = h + row * C_;
  #pragma unroll
  for (int i = 0; i < 6; i++) {
    float hv = (v0[i] - mu) * rs * g[c0 + i] + b[c0 + i];
    hr[c0 + i] = f2bf(hv);
  }
}

// ------------------------------------------------------------- MFMA GEMM 128
// out[M,N] = act(A[M,K](bf16) @ Wt^T + bias) [+ resid]; Wt bf16 [N][K].
// M%128==0, N%128==0, K%32==0. 1-D grid mT*nT, XCD swizzle when mT%8==0.
// Double-buffered LDS: one barrier per k-iter.
template<int RELU, int RES, int OBF>
__global__ __launch_bounds__(256) void gemm128d(const u16* __restrict__ A,
    const u16* __restrict__ Wt, const float* __restrict__ bias,
    const float* __restrict__ resid, void* __restrict__ outp,
    int N, int K, int mT, int nT)
{
  __shared__ __align__(16) u16 As[2][4][128][8];   // 16 KB
  __shared__ __align__(16) u16 Bs[2][4][128][8];   // 16 KB
  int tid = threadIdx.x;
  int bid = blockIdx.x;
  int mtile, ntile;
  if ((mT & 7) == 0) {
    int xcd = bid & 7, loc = bid >> 3;
    int q = loc / nT;
    mtile = xcd * (mT >> 3) + q;
    ntile = loc - q * nT;
  } else {
    int q = bid / nT;
    mtile = q;
    ntile = bid - q * nT;
  }
  long mBase = (long)mtile * 128;
  int  nBase = ntile * 128;
  int lane = tid & 63, wv = tid >> 6;
  int l15 = lane & 15, l4 = lane >> 4;
  int sk = tid & 3, sr = tid >> 2;
  const u16* aP = A + (mBase + sr) * (long)K + sk * 8;
  const u16* bP = Wt + ((long)nBase + sr) * K + sk * 8;
  const long rStep = (long)64 * K;

  f32x4 acc[2][8];
  #pragma unroll
  for (int i = 0; i < 2; i++)
    #pragma unroll
    for (int j = 0; j < 8; j++)
      acc[i][j] = (f32x4){0.f, 0.f, 0.f, 0.f};

  // stage k=0 into buf0
  uint4 ar0 = *(const uint4*)aP;
  uint4 ar1 = *(const uint4*)(aP + rStep);
  uint4 br0 = *(const uint4*)bP;
  uint4 br1 = *(const uint4*)(bP + rStep);
  *(uint4*)&As[0][sk][sr][0]      = ar0;
  *(uint4*)&As[0][sk][sr + 64][0] = ar1;
  *(uint4*)&Bs[0][sk][sr][0]      = br0;
  *(uint4*)&Bs[0][sk][sr + 64][0] = br1;
  if (K > 32) {                       // preload k=32 regs
    ar0 = *(const uint4*)(aP + 32);
    ar1 = *(const uint4*)(aP + rStep + 32);
    br0 = *(const uint4*)(bP + 32);
    br1 = *(const uint4*)(bP + rStep + 32);
  }
  __syncthreads();

  int cur = 0;
  for (int k0 = 0; k0 < K; k0 += 32) {
    bf16x8 af[2], bfr[8];
    af[0] = *(const bf16x8*)&As[cur][l4][wv * 32 + l15][0];
    af[1] = *(const bf16x8*)&As[cur][l4][wv * 32 + 16 + l15][0];
    #pragma unroll
    for (int j = 0; j < 8; j++)
      bfr[j] = *(const bf16x8*)&Bs[cur][l4][j * 16 + l15][0];
    if (k0 + 32 < K) {                // stage next buf from regs
      int nb = cur ^ 1;
      *(uint4*)&As[nb][sk][sr][0]      = ar0;
      *(uint4*)&As[nb][sk][sr + 64][0] = ar1;
      *(uint4*)&Bs[nb][sk][sr][0]      = br0;
      *(uint4*)&Bs[nb][sk][sr + 64][0] = br1;
      if (k0 + 64 < K) {              // load k0+64 regs under the MFMAs
        ar0 = *(const uint4*)(aP + k0 + 64);
        ar1 = *(const uint4*)(aP + rStep + k0 + 64);
        br0 = *(const uint4*)(bP + k0 + 64);
        br1 = *(const uint4*)(bP + rStep + k0 + 64);
      }
    }
    #pragma unroll
    for (int i = 0; i < 2; i++)
      #pragma unroll
      for (int j = 0; j < 8; j++)
        acc[i][j] = __builtin_amdgcn_mfma_f32_16x16x32_bf16(
            af[i], bfr[j], acc[i][j], 0, 0, 0);
    __syncthreads();                  // single barrier per iter
    cur ^= 1;
  }

  #pragma unroll
  for (int i = 0; i < 2; i++) {
    #pragma unroll
    for (int j = 0; j < 8; j++) {
      int n = nBase + j * 16 + l15;
      float bv = bias ? bias[n] : 0.f;
      #pragma unroll
      for (int r = 0; r < 4; r++) {
        long row = mBase + wv * 32 + i * 16 + l4 * 4 + r;
        float vv = acc[i][j][r] + bv;
        if (RELU) vv = fmaxf(vv, 0.f);
        if (RES)  vv += resid[row * N + n];
        if (OBF) ((u16*)outp)[row * N + n] = f2bf(vv);
        else     ((float*)outp)[row * N + n] = vv;
      }
    }
  }
}

// ------------------------------------------------------------- head GEMM
template<int OBF>
__global__ __launch_bounds__(256) void gemm_head(const u16* __restrict__ A,
    const u16* __restrict__ Wt, const float* __restrict__ bias,
    void* __restrict__ outp, int N, int K)
{
  __shared__ __align__(16) u16 As[4][128][8];
  __shared__ __align__(16) u16 Bs[4][64][8];
  int tid  = threadIdx.x;
  int nt   = blockIdx.x;
  int nBase = nt * 64;
  long mBase = (long)blockIdx.y * 128;
  int lane = tid & 63, wv = tid >> 6;
  int l15 = lane & 15, l4 = lane >> 4;
  int sseg = tid & 3;
  int srow = tid >> 2;
  const u16* a0p = A + (mBase + srow) * K + sseg * 8;
  const u16* a1p = a0p + (long)64 * K;
  bool colOK = (nBase + srow) < N;
  const u16* bp  = Wt + (long)(nBase + srow) * K + sseg * 8;

  f32x4 acc[2][4];
  #pragma unroll
  for (int i = 0; i < 2; i++)
    #pragma unroll
    for (int j = 0; j < 4; j++)
      acc[i][j] = (f32x4){0.f, 0.f, 0.f, 0.f};

  for (int k0 = 0; k0 < K; k0 += 32) {
    uint4 av0 = *(const uint4*)(a0p + k0);
    uint4 av1 = *(const uint4*)(a1p + k0);
    uint4 bv  = colOK ? *(const uint4*)(bp + k0) : make_uint4(0, 0, 0, 0);
    *(uint4*)&As[sseg][srow][0]      = av0;
    *(uint4*)&As[sseg][srow + 64][0] = av1;
    *(uint4*)&Bs[sseg][srow][0]      = bv;
    __syncthreads();
    bf16x8 af[2], bfr[4];
    af[0] = *(const bf16x8*)&As[l4][wv * 32 + l15][0];
    af[1] = *(const bf16x8*)&As[l4][wv * 32 + 16 + l15][0];
    #pragma unroll
    for (int j = 0; j < 4; j++)
      bfr[j] = *(const bf16x8*)&Bs[l4][j * 16 + l15][0];
    #pragma unroll
    for (int i = 0; i < 2; i++)
      #pragma unroll
      for (int j = 0; j < 4; j++)
        acc[i][j] = __builtin_amdgcn_mfma_f32_16x16x32_bf16(
            af[i], bfr[j], acc[i][j], 0, 0, 0);
    __syncthreads();
  }

  #pragma unroll
  for (int i = 0; i < 2; i++) {
    #pragma unroll
    for (int j = 0; j < 4; j++) {
      int n = nBase + j * 16 + l15;
      if (n < N) {
        #pragma unroll
        for (int r = 0; r < 4; r++) {
          long row = mBase + wv * 32 + i * 16 + l4 * 4 + r;
          float vv = acc[i][j][r];
          if (bias) vv += bias[n];
          if (OBF) ((u16*)outp)[row * N + n] = f2bf(vv);
          else     ((float*)outp)[row * N + n] = vv;
        }
      }
    }
  }
}

// ---------------------------------------------------------------- attention
// MFMA flash-style: one block per (b, head); qkv [BTc][1152]; ao [BTc][384].
__global__ __launch_bounds__(256) void attn_k(const u16* __restrict__ qkv,
    u16* __restrict__ ao)
{
  __shared__ __align__(16) u16 qs[64][72];
  __shared__ __align__(16) u16 ks[64][72];
  __shared__ __align__(16) u16 vT[64][72];
  __shared__ __align__(16) u16 ps[64][72];
  int tid = threadIdx.x;
  int bb = blockIdx.x / H_;
  int hh = blockIdx.x % H_;
  const u16* base = qkv + ((long)bb * T_) * 1152 + hh * HS_;

  for (int i = tid; i < 576; i += 256)
    ((uint4*)vT)[i] = make_uint4(0, 0, 0, 0);
  __syncthreads();

  for (int i = tid; i < 480; i += 256) {
    int t = i >> 3, d0 = (i & 7) << 3;
    const u16* rp = base + (long)t * 1152;
    *(uint4*)&qs[t][d0] = *(const uint4*)(rp + d0);
    *(uint4*)&ks[t][d0] = *(const uint4*)(rp + 384 + d0);
    uint4 rv = *(const uint4*)(rp + 768 + d0);
    u16 vv[8] = {(u16)(rv.x & 0xffffu), (u16)(rv.x >> 16),
                 (u16)(rv.y & 0xffffu), (u16)(rv.y >> 16),
                 (u16)(rv.z & 0xffffu), (u16)(rv.z >> 16),
                 (u16)(rv.w & 0xffffu), (u16)(rv.w >> 16)};
    #pragma unroll
    for (int m = 0; m < 8; m++) vT[d0 + m][t] = vv[m];
  }
  __syncthreads();

  int lane = tid & 63, wv = tid >> 6;
  int l15 = lane & 15, quad = lane >> 4;

  bf16x8 aq0 = *(const bf16x8*)&qs[wv * 16 + l15][quad * 8];
  bf16x8 aq1 = *(const bf16x8*)&qs[wv * 16 + l15][32 + quad * 8];
  f32x4 s[4];
  #pragma unroll
  for (int jt = 0; jt < 4; jt++) {
    bf16x8 b0 = *(const bf16x8*)&ks[jt * 16 + l15][quad * 8];
    bf16x8 b1 = *(const bf16x8*)&ks[jt * 16 + l15][32 + quad * 8];
    f32x4 a2 = (f32x4){0.f, 0.f, 0.f, 0.f};
    a2 = __builtin_amdgcn_mfma_f32_16x16x32_bf16(aq0, b0, a2, 0, 0, 0);
    a2 = __builtin_amdgcn_mfma_f32_16x16x32_bf16(aq1, b1, a2, 0, 0, 0);
    s[jt] = a2;
  }

  int rbase = wv * 16 + quad * 4;
  #pragma unroll
  for (int r = 0; r < 4; r++) {
    int row = rbase + r;
    float v0[4];
    #pragma unroll
    for (int jt = 0; jt < 4; jt++) {
      int col = jt * 16 + l15;
      float sv = s[jt][r] * 0.125f;
      v0[jt] = (col <= row) ? sv : -1e30f;
    }
    float m = fmaxf(fmaxf(v0[0], v0[1]), fmaxf(v0[2], v0[3]));
    #pragma unroll
    for (int off = 1; off < 16; off <<= 1) m = fmaxf(m, __shfl_xor(m, off, 64));
    float sum = 0.f;
    #pragma unroll
    for (int jt = 0; jt < 4; jt++) { v0[jt] = __expf(v0[jt] - m); sum += v0[jt]; }
    #pragma unroll
    for (int off = 1; off < 16; off <<= 1) sum += __shfl_xor(sum, off, 64);
    float inv = 1.f / sum;
    #pragma unroll
    for (int jt = 0; jt < 4; jt++)
      ps[row][jt * 16 + l15] = f2bf(v0[jt] * inv);
  }
  __syncthreads();

  bf16x8 ap0 = *(const bf16x8*)&ps[wv * 16 + l15][quad * 8];
  bf16x8 ap1 = *(const bf16x8*)&ps[wv * 16 + l15][32 + quad * 8];
  long obase = ((long)bb * T_) * C_ + hh * HS_;
  #pragma unroll
  for (int dt = 0; dt < 4; dt++) {
    bf16x8 b0 = *(const bf16x8*)&vT[dt * 16 + l15][quad * 8];
    bf16x8 b1 = *(const bf16x8*)&vT[dt * 16 + l15][32 + quad * 8];
    f32x4 a2 = (f32x4){0.f, 0.f, 0.f, 0.f};
    a2 = __builtin_amdgcn_mfma_f32_16x16x32_bf16(ap0, b0, a2, 0, 0, 0);
    a2 = __builtin_amdgcn_mfma_f32_16x16x32_bf16(ap1, b1, a2, 0, 0, 0);
    #pragma unroll
    for (int r = 0; r < 4; r++) {
      int row = rbase + r;
      if (row < T_)
        ao[obase + (long)row * C_ + dt * 16 + l15] = f2bf(a2[r]);
    }
  }
}

// ---------------------------------------------------------------- launch
extern "C" void kernel_launch(void* const* d_in, const int* in_sizes, int n_in,
                              void* d_out, int out_size, void* d_ws, size_t ws_size,
                              hipStream_t stream)
{
  const int*   ctx  = (const int*)  d_in[0];
  const float* tok  = (const float*)d_in[1];
  const float* pos  = (const float*)d_in[2];
  const float* wq   = (const float*)d_in[3];
  const float* wk   = (const float*)d_in[4];
  const float* wv   = (const float*)d_in[5];
  const float* wo   = (const float*)d_in[6];
  const float* bo   = (const float*)d_in[7];
  const float* ln1g = (const float*)d_in[8];
  const float* ln1b = (const float*)d_in[9];
  const float* ln2g = (const float*)d_in[10];
  const float* ln2b = (const float*)d_in[11];
  const float* w1   = (const float*)d_in[12];
  const float* b1   = (const float*)d_in[13];
  const float* w2   = (const float*)d_in[14];
  const float* b2   = (const float*)d_in[15];
  const float* lnfg = (const float*)d_in[16];
  const float* lnfb = (const float*)d_in[17];
  const float* lmw  = (const float*)d_in[18];
  const float* lmb  = (const float*)d_in[19];
  float* out = (float*)d_out;

  const long nQKV = (long)L_ * H_ * C_ * HS_;
  const long nWO  = (long)L_ * C_ * C_;
  const long nW1  = (long)L_ * C_ * FF_;
  const long nLM  = (long)C_ * V_;
  u16* wqkvT = (u16*)d_ws;                       // [L][1152][384]
  u16* woT = wqkvT + 3 * nQKV;
  u16* w1T = woT + nWO;
  u16* w2T = w1T + nW1;
  u16* lmT = w2T + nW1;
  const size_t wbytes = (size_t)(nQKV * 3 + nWO + nW1 * 2 + nLM) * 2;

  int chunkB = 32;
  {
    const int cand[] = {2048, 1024, 512, 256, 128, 64, 32};
    for (int i = 0; i < 7; i++) {
      size_t U = (size_t)cand[i] * T_ * C_ * 2;
      if (wbytes + 7 * U <= ws_size) { chunkB = cand[i]; break; }
    }
  }
  const long BTc = (long)chunkB * T_;
  char* wsb = (char*)d_ws + wbytes;
  const size_t U = (size_t)BTc * C_ * 2;
  float* x    = (float*)wsb;             // 2U
  u16*   h    = (u16*)(wsb + 2 * U);     // 1U
  char*  reg  = wsb + 3 * U;             // 4U: qkv(3U) + ab(1U); fb aliases
  u16* qkvb = (u16*)reg;
  u16* ab   = (u16*)(reg + 3 * U);
  u16* fb   = (u16*)reg;                 // alias: qkv/ab dead before MLP

  {
    dim3 tb(32, 8);
    const long sL = 1152L * 384, sH = 64L * 384, sec = 384L * 384;
    tconv_k<<<dim3(2, 12, L_ * H_), tb, 0, stream>>>(wq, wqkvT,
        C_, HS_, (long)C_ * HS_, H_, sL, sH);
    tconv_k<<<dim3(2, 12, L_ * H_), tb, 0, stream>>>(wk, wqkvT + sec,
        C_, HS_, (long)C_ * HS_, H_, sL, sH);
    tconv_k<<<dim3(2, 12, L_ * H_), tb, 0, stream>>>(wv, wqkvT + 2 * sec,
        C_, HS_, (long)C_ * HS_, H_, sL, sH);
    tconv_k<<<dim3(12, 12, L_), tb, 0, stream>>>(wo, woT,
        C_, C_, (long)C_ * C_, 1, (long)C_ * C_, 0);
    tconv_k<<<dim3(48, 12, L_), tb, 0, stream>>>(w1, w1T,
        C_, FF_, (long)C_ * FF_, 1, (long)C_ * FF_, 0);
    tconv_k<<<dim3(12, 48, L_), tb, 0, stream>>>(w2, w2T,
        FF_, C_, (long)FF_ * C_, 1, (long)FF_ * C_, 0);
    tconv_k<<<dim3(3, 12, 1), tb, 0, stream>>>(lmw, lmT,
        C_, V_, (long)C_ * V_, 1, 0, 0);
  }

  const long qkvL = 1152L * 384;
  const long woL  = (long)C_ * C_;
  const long w1L  = (long)C_ * FF_;
  dim3 blk(256);
  dim3 gEmb((u32)(BTc * C_ / 4 / 256));
  dim3 gLN((u32)(BTc / 4));
  int mT = (int)(BTc / 128);
  dim3 gHd(2, (u32)(BTc / 128));
  dim3 gAt((u32)(chunkB * H_));

  for (int c0 = 0; c0 < B_; c0 += chunkB) {
    const long tok0 = (long)c0 * T_;
    const int* ctxc = ctx + tok0;
    float* outc = out + tok0 * V_;

    embed_k<<<gEmb, blk, 0, stream>>>(ctxc, tok, pos, x);

    for (int l = 0; l < L_; l++) {
      ln_k<<<gLN, blk, 0, stream>>>(x, ln1g + l * C_, ln1b + l * C_, h);
      gemm128d<0,0,1><<<dim3(mT * 9), blk, 0, stream>>>(h, wqkvT + l * qkvL,
          nullptr, nullptr, qkvb, 1152, C_, mT, 9);
      attn_k<<<gAt, blk, 0, stream>>>(qkvb, ab);
      gemm128d<0,1,0><<<dim3(mT * 3), blk, 0, stream>>>(ab, woT + l * woL,
          bo + l * C_, x, x, C_, C_, mT, 3);
      ln_k<<<gLN, blk, 0, stream>>>(x, ln2g + l * C_, ln2b + l * C_, h);
      gemm128d<1,0,1><<<dim3(mT * 12), blk, 0, stream>>>(h, w1T + l * w1L,
          b1 + l * FF_, nullptr, fb, FF_, C_, mT, 12);
      gemm128d<0,1,0><<<dim3(mT * 3), blk, 0, stream>>>(fb, w2T + l * w1L,
          b2 + l * C_, x, x, C_, FF_, mT, 3);
    }

    ln_k<<<gLN, blk, 0, stream>>>(x, lnfg, lnfb, h);
    gemm_head<0><<<gHd, blk, 0, stream>>>(h, lmT, lmb, outc, V_, C_);
  }
}